// Round 3
// baseline (408.273 us; speedup 1.0000x reference)
//
#include <hip/hip_runtime.h>
#include <hip/hip_bf16.h>

typedef __bf16 bf16_t;
typedef __bf16 bf16x8 __attribute__((ext_vector_type(8)));
typedef float f32x4 __attribute__((ext_vector_type(4)));

// ---------------------------------------------------------------------------
// Weight transposes with f32 -> bf16 convert: W[din][dout] -> WT[dout][din]
// ---------------------------------------------------------------------------
__global__ void transpose_qkvw_kernel(const float* __restrict__ wq, const float* __restrict__ wk,
                                      const float* __restrict__ wv, bf16_t* __restrict__ wqkvT)
{
    __shared__ bf16_t tile[64][65];
    int z = blockIdx.z;
    const float* src = (z == 0) ? wq : (z == 1) ? wk : wv;
    bf16_t* dst = wqkvT + (size_t)z * 1048576;
    int rB = blockIdx.y * 64, cB = blockIdx.x * 64;
    int t = threadIdx.x;
#pragma unroll
    for (int i = 0; i < 16; i++) {
        int e = t + i * 256; int r = e >> 6, c = e & 63;
        tile[r][c] = (bf16_t)src[(size_t)(rB + r) * 1024 + cB + c];
    }
    __syncthreads();
#pragma unroll
    for (int i = 0; i < 16; i++) {
        int e = t + i * 256; int r = e >> 6, c = e & 63;
        dst[(size_t)(cB + r) * 1024 + rB + c] = tile[c][r];
    }
}

__global__ void transpose_one_kernel(const float* __restrict__ src, bf16_t* __restrict__ dst)
{
    __shared__ bf16_t tile[64][65];
    int rB = blockIdx.y * 64, cB = blockIdx.x * 64;
    int t = threadIdx.x;
#pragma unroll
    for (int i = 0; i < 16; i++) {
        int e = t + i * 256; int r = e >> 6, c = e & 63;
        tile[r][c] = (bf16_t)src[(size_t)(rB + r) * 1024 + cB + c];
    }
    __syncthreads();
#pragma unroll
    for (int i = 0; i < 16; i++) {
        int e = t + i * 256; int r = e >> 6, c = e & 63;
        dst[(size_t)(cB + r) * 1024 + rB + c] = tile[c][r];
    }
}

__global__ void transpose_small_kernel(const float* __restrict__ s0, const float* __restrict__ s1,
                                       const float* __restrict__ s2,
                                       bf16_t* __restrict__ d0, bf16_t* __restrict__ d1, bf16_t* __restrict__ d2)
{
    int z = blockIdx.x;
    const float* src = (z == 0) ? s0 : (z == 1) ? s1 : s2;
    bf16_t* dst = (z == 0) ? d0 : (z == 1) ? d1 : d2;
    int t = threadIdx.x;
#pragma unroll
    for (int i = 0; i < 16; i++) {
        int e = t + i * 256; int r = e >> 6, c = e & 63;
        dst[c * 64 + r] = (bf16_t)src[r * 64 + c];
    }
}

// ---------------------------------------------------------------------------
// QKV GEMM: A is f32 [4096][1024], Bt (weights^T) bf16 [1024][1024].
// 128x128 C-tile, BK=32, 4 waves, 4x4 16x16x32 bf16 MFMA frags.
// Q/K -> [B,H,L,DK]; V -> [B,H,DK,L] (transposed for flash B-frags)
// ---------------------------------------------------------------------------
__global__ __launch_bounds__(256, 2) void gemm_qkv_kernel(
    const float* __restrict__ Aq, const float* __restrict__ Ak, const float* __restrict__ Av,
    const bf16_t* __restrict__ WT,
    const float* __restrict__ bq, const float* __restrict__ bk, const float* __restrict__ bv,
    bf16_t* __restrict__ outbase)
{
    __shared__ bf16_t As[4096];
    __shared__ bf16_t Bs[4096];
    const int z = blockIdx.z;
    const float* A    = (z == 0) ? Aq : (z == 1) ? Ak : Av;
    const bf16_t* Bt  = WT + (size_t)z * 1048576;
    const float* bia  = (z == 0) ? bq : (z == 1) ? bk : bv;
    bf16_t* out = outbase + (size_t)z * 4194304;

    const int t = threadIdx.x;
    const int w = t >> 6, lane = t & 63;
    const int lane15 = lane & 15, quad = lane >> 4;
    const int wr = w >> 1, wc = w & 1;
    const int rowBase = blockIdx.y * 128, colBase = blockIdx.x * 128;

    // A staging map: thread t -> row t>>1, cols (t&1)*16 + [0,16)  (f32 -> bf16)
    const int ar = t >> 1, ac = (t & 1) * 16;
    // B staging map: elements e0/e1 of [128][32] bf16 tile
    const int e0 = t * 8, e1 = (256 + t) * 8;
    const int r0 = e0 >> 5, c0 = e0 & 31;
    const int r1 = e1 >> 5, c1 = e1 & 31;

    f32x4 acc[4][4];
    f32x4 zf = {0.f, 0.f, 0.f, 0.f};
#pragma unroll
    for (int i = 0; i < 4; i++)
#pragma unroll
        for (int j = 0; j < 4; j++) acc[i][j] = zf;

    for (int k0 = 0; k0 < 1024; k0 += 32) {
        const float4* ap = (const float4*)(A + (size_t)(rowBase + ar) * 1024 + k0 + ac);
        float4 af4[4];
#pragma unroll
        for (int i = 0; i < 4; i++) af4[i] = ap[i];
        bf16x8 b0 = *(const bf16x8*)(Bt + (size_t)(colBase + r0) * 1024 + k0 + c0);
        bf16x8 b1 = *(const bf16x8*)(Bt + (size_t)(colBase + r1) * 1024 + k0 + c1);
        bf16x8 av0, av1;
#pragma unroll
        for (int i = 0; i < 4; i++) {
            bf16x8& dstv = (i < 2) ? av0 : av1;
            int base = (i & 1) * 4;
            dstv[base + 0] = (bf16_t)af4[i].x; dstv[base + 1] = (bf16_t)af4[i].y;
            dstv[base + 2] = (bf16_t)af4[i].z; dstv[base + 3] = (bf16_t)af4[i].w;
        }
        *(bf16x8*)(As + ar * 32 + ac) = av0;
        *(bf16x8*)(As + ar * 32 + ac + 8) = av1;
        *(bf16x8*)(Bs + e0) = b0;
        *(bf16x8*)(Bs + e1) = b1;
        __syncthreads();
        bf16x8 afr[4], bfr[4];
#pragma unroll
        for (int mi = 0; mi < 4; mi++)
            afr[mi] = *(const bf16x8*)(As + (wr * 64 + mi * 16 + lane15) * 32 + quad * 8);
#pragma unroll
        for (int ni = 0; ni < 4; ni++)
            bfr[ni] = *(const bf16x8*)(Bs + (wc * 64 + ni * 16 + lane15) * 32 + quad * 8);
#pragma unroll
        for (int mi = 0; mi < 4; mi++)
#pragma unroll
            for (int ni = 0; ni < 4; ni++)
                acc[mi][ni] = __builtin_amdgcn_mfma_f32_16x16x32_bf16(afr[mi], bfr[ni], acc[mi][ni], 0, 0, 0);
        __syncthreads();
    }

#pragma unroll
    for (int ni = 0; ni < 4; ni++) {
        int col = colBase + wc * 64 + ni * 16 + lane15;   // dout
        float bias = bia[col];
        int h = col >> 6, dk = col & 63;
#pragma unroll
        for (int mi = 0; mi < 4; mi++) {
#pragma unroll
            for (int r = 0; r < 4; r++) {
                int row = rowBase + wr * 64 + mi * 16 + quad * 4 + r;
                int b = row >> 11, l = row & 2047;
                float v = acc[mi][ni][r] + bias;
                size_t dst = (z < 2) ? ((((size_t)(b * 16 + h)) * 2048 + l) * 64 + dk)
                                     : ((((size_t)(b * 16 + h)) * 64 + dk) * 2048 + l);
                out[dst] = (bf16_t)v;
            }
        }
    }
}

// ---------------------------------------------------------------------------
// Output projection: A (concat) bf16 [4096][1024], Bt (woT) bf16, out f32.
// ---------------------------------------------------------------------------
__global__ __launch_bounds__(256, 2) void gemm_out_kernel(
    const bf16_t* __restrict__ A, const bf16_t* __restrict__ Bt,
    const float* __restrict__ bia, float* __restrict__ out)
{
    __shared__ bf16_t As[4096];
    __shared__ bf16_t Bs[4096];
    const int t = threadIdx.x;
    const int w = t >> 6, lane = t & 63;
    const int lane15 = lane & 15, quad = lane >> 4;
    const int wr = w >> 1, wc = w & 1;
    const int rowBase = blockIdx.y * 128, colBase = blockIdx.x * 128;
    const int e0 = t * 8, e1 = (256 + t) * 8;
    const int r0 = e0 >> 5, c0 = e0 & 31;
    const int r1 = e1 >> 5, c1 = e1 & 31;

    f32x4 acc[4][4];
    f32x4 zf = {0.f, 0.f, 0.f, 0.f};
#pragma unroll
    for (int i = 0; i < 4; i++)
#pragma unroll
        for (int j = 0; j < 4; j++) acc[i][j] = zf;

    for (int k0 = 0; k0 < 1024; k0 += 32) {
        bf16x8 a0 = *(const bf16x8*)(A  + (size_t)(rowBase + r0) * 1024 + k0 + c0);
        bf16x8 a1 = *(const bf16x8*)(A  + (size_t)(rowBase + r1) * 1024 + k0 + c1);
        bf16x8 b0 = *(const bf16x8*)(Bt + (size_t)(colBase + r0) * 1024 + k0 + c0);
        bf16x8 b1 = *(const bf16x8*)(Bt + (size_t)(colBase + r1) * 1024 + k0 + c1);
        *(bf16x8*)(As + e0) = a0;
        *(bf16x8*)(As + e1) = a1;
        *(bf16x8*)(Bs + e0) = b0;
        *(bf16x8*)(Bs + e1) = b1;
        __syncthreads();
        bf16x8 afr[4], bfr[4];
#pragma unroll
        for (int mi = 0; mi < 4; mi++)
            afr[mi] = *(const bf16x8*)(As + (wr * 64 + mi * 16 + lane15) * 32 + quad * 8);
#pragma unroll
        for (int ni = 0; ni < 4; ni++)
            bfr[ni] = *(const bf16x8*)(Bs + (wc * 64 + ni * 16 + lane15) * 32 + quad * 8);
#pragma unroll
        for (int mi = 0; mi < 4; mi++)
#pragma unroll
            for (int ni = 0; ni < 4; ni++)
                acc[mi][ni] = __builtin_amdgcn_mfma_f32_16x16x32_bf16(afr[mi], bfr[ni], acc[mi][ni], 0, 0, 0);
        __syncthreads();
    }

#pragma unroll
    for (int ni = 0; ni < 4; ni++) {
        int col = colBase + wc * 64 + ni * 16 + lane15;
        float bias = bia[col];
#pragma unroll
        for (int mi = 0; mi < 4; mi++) {
#pragma unroll
            for (int r = 0; r < 4; r++) {
                int row = rowBase + wr * 64 + mi * 16 + quad * 4 + r;
                out[(size_t)row * 1024 + col] = acc[mi][ni][r] + bias;
            }
        }
    }
}

// ---------------------------------------------------------------------------
// Flash attention: one block per (qtile64, bh); 4 waves x 16 q-rows.
// Q,K bf16 [B,H,L,DK]; V bf16 transposed [B,H,DK,L]. scale=0.125 on Q (exact).
// ---------------------------------------------------------------------------
__global__ __launch_bounds__(256, 2) void flash_kernel(
    const bf16_t* __restrict__ QKV, const int* __restrict__ mask,
    bf16_t* __restrict__ attnout)
{
    __shared__ bf16_t Ks[4096];
    __shared__ bf16_t Vs[4096];
    __shared__ bf16_t Ps[4096];
    const int t = threadIdx.x, w = t >> 6, lane = t & 63;
    const int lane15 = lane & 15, quad = lane >> 4;
    const int qt = blockIdx.x, bh = blockIdx.y;
    const int b = bh >> 4;
    const bf16_t* Q  = QKV;
    const bf16_t* K  = QKV + 4194304;
    const bf16_t* Vt = QKV + 8388608;
    const int qrow0 = qt * 64 + w * 16;

    const bf16_t* qb = Q + ((size_t)bh * 2048 + qrow0 + lane15) * 64;
    bf16x8 aq0 = *(const bf16x8*)(qb + quad * 8);
    bf16x8 aq1 = *(const bf16x8*)(qb + 32 + quad * 8);
#pragma unroll
    for (int j = 0; j < 8; j++) {       // exact: *2^-3
        aq0[j] = (bf16_t)((float)aq0[j] * 0.125f);
        aq1[j] = (bf16_t)((float)aq1[j] * 0.125f);
    }

    f32x4 o[4];
    f32x4 zf = {0.f, 0.f, 0.f, 0.f};
#pragma unroll
    for (int df = 0; df < 4; df++) o[df] = zf;
    float m_i[4], l_i[4];
#pragma unroll
    for (int r = 0; r < 4; r++) { m_i[r] = -1e30f; l_i[r] = 0.f; }
    bf16_t* Pw = Ps + w * 1024;

    const int e0 = t * 8, e1 = (256 + t) * 8;
    const int kr0 = e0 >> 6, kc0 = e0 & 63, kr1 = e1 >> 6, kc1 = e1 & 63;

    for (int kt = 0; kt < 32; kt++) {
        bf16x8 k0v = *(const bf16x8*)(K  + ((size_t)bh * 2048 + kt * 64 + kr0) * 64 + kc0);
        bf16x8 k1v = *(const bf16x8*)(K  + ((size_t)bh * 2048 + kt * 64 + kr1) * 64 + kc1);
        bf16x8 v0v = *(const bf16x8*)(Vt + ((size_t)bh * 64 + kr0) * 2048 + kt * 64 + kc0);
        bf16x8 v1v = *(const bf16x8*)(Vt + ((size_t)bh * 64 + kr1) * 2048 + kt * 64 + kc1);
        *(bf16x8*)(Ks + e0) = k0v;
        *(bf16x8*)(Ks + e1) = k1v;
        *(bf16x8*)(Vs + e0) = v0v;
        *(bf16x8*)(Vs + e1) = v1v;
        __syncthreads();

        f32x4 sf[4];
#pragma unroll
        for (int nf = 0; nf < 4; nf++) {
            f32x4 a = zf;
            bf16x8 kb0 = *(const bf16x8*)(Ks + (nf * 16 + lane15) * 64 + quad * 8);
            bf16x8 kb1 = *(const bf16x8*)(Ks + (nf * 16 + lane15) * 64 + 32 + quad * 8);
            a = __builtin_amdgcn_mfma_f32_16x16x32_bf16(aq0, kb0, a, 0, 0, 0);
            a = __builtin_amdgcn_mfma_f32_16x16x32_bf16(aq1, kb1, a, 0, 0, 0);
            sf[nf] = a;
        }
        // per-element mask (correctness round; mask is L3-resident)
#pragma unroll
        for (int nf = 0; nf < 4; nf++)
#pragma unroll
            for (int r = 0; r < 4; r++) {
                int qrow = qrow0 + quad * 4 + r;
                int kpos = kt * 64 + nf * 16 + lane15;
                if (mask[((size_t)b * 2048 + qrow) * 2048 + kpos] == 0)
                    sf[nf][r] = -1e30f;
            }
        float alpha[4], pf[4][4];
#pragma unroll
        for (int r = 0; r < 4; r++) {
            float mx = fmaxf(fmaxf(sf[0][r], sf[1][r]), fmaxf(sf[2][r], sf[3][r]));
            mx = fmaxf(mx, __shfl_xor(mx, 1));
            mx = fmaxf(mx, __shfl_xor(mx, 2));
            mx = fmaxf(mx, __shfl_xor(mx, 4));
            mx = fmaxf(mx, __shfl_xor(mx, 8));
            float mn = fmaxf(m_i[r], mx);
            alpha[r] = __expf(m_i[r] - mn);
            m_i[r] = mn;
            float rs = 0.f;
#pragma unroll
            for (int nf = 0; nf < 4; nf++) { float pv = __expf(sf[nf][r] - mn); pf[nf][r] = pv; rs += pv; }
            rs += __shfl_xor(rs, 1);
            rs += __shfl_xor(rs, 2);
            rs += __shfl_xor(rs, 4);
            rs += __shfl_xor(rs, 8);
            l_i[r] = l_i[r] * alpha[r] + rs;
        }
#pragma unroll
        for (int nf = 0; nf < 4; nf++)
#pragma unroll
            for (int r = 0; r < 4; r++)
                Pw[(quad * 4 + r) * 64 + nf * 16 + lane15] = (bf16_t)pf[nf][r];
        __syncthreads();   // P C-layout -> A-layout round trip

        bf16x8 pa0 = *(const bf16x8*)(Pw + lane15 * 64 + quad * 8);
        bf16x8 pa1 = *(const bf16x8*)(Pw + lane15 * 64 + 32 + quad * 8);
#pragma unroll
        for (int df = 0; df < 4; df++) {
            f32x4 oo = o[df];
#pragma unroll
            for (int r = 0; r < 4; r++) oo[r] *= alpha[r];
            bf16x8 vb0 = *(const bf16x8*)(Vs + (df * 16 + lane15) * 64 + quad * 8);
            bf16x8 vb1 = *(const bf16x8*)(Vs + (df * 16 + lane15) * 64 + 32 + quad * 8);
            oo = __builtin_amdgcn_mfma_f32_16x16x32_bf16(pa0, vb0, oo, 0, 0, 0);
            oo = __builtin_amdgcn_mfma_f32_16x16x32_bf16(pa1, vb1, oo, 0, 0, 0);
            o[df] = oo;
        }
        __syncthreads();   // all waves done reading Ks/Vs before restage
    }
#pragma unroll
    for (int df = 0; df < 4; df++)
#pragma unroll
        for (int r = 0; r < 4; r++) {
            float v = o[df][r] / l_i[r];
            attnout[((size_t)bh * 2048 + qrow0 + quad * 4 + r) * 64 + df * 16 + lane15] = (bf16_t)v;
        }
}

// ---------------------------------------------------------------------------
// Inter-head attention: one wave per position (b,l). heads[16,64] per position.
// ---------------------------------------------------------------------------
__global__ __launch_bounds__(256, 2) void interhead_kernel(
    const bf16_t* __restrict__ attn,
    const bf16_t* __restrict__ whqT, const float* __restrict__ bhq,
    const bf16_t* __restrict__ whkT, const float* __restrict__ bhk,
    const bf16_t* __restrict__ whvT, const float* __restrict__ bhv,
    bf16_t* __restrict__ concat)
{
    __shared__ bf16_t lds[4 * 4608];
    const int t = threadIdx.x, w = t >> 6, lane = t & 63;
    const int lane15 = lane & 15, quad = lane >> 4;
    bf16_t* Qh  = lds + w * 4608;   // [16][64]
    bf16_t* Kh  = Qh + 1024;        // [16][64]
    bf16_t* VhT = Kh + 1024;        // [64][32] (k-padded)
    bf16_t* P16 = VhT + 2048;       // [16][32] (k-padded)
    const int p = blockIdx.x * 4 + w;
    const int b = p >> 11, l = p & 2047;

    bf16x8 z8 = {(bf16_t)0.f, (bf16_t)0.f, (bf16_t)0.f, (bf16_t)0.f,
                 (bf16_t)0.f, (bf16_t)0.f, (bf16_t)0.f, (bf16_t)0.f};
    ((bf16x8*)P16)[lane] = z8;
#pragma unroll
    for (int i = 0; i < 4; i++) ((bf16x8*)VhT)[i * 64 + lane] = z8;

    const bf16_t* hb = attn + ((size_t)(b * 16 + lane15) * 2048 + l) * 64;
    bf16x8 ha0 = *(const bf16x8*)(hb + quad * 8);
    bf16x8 ha1 = *(const bf16x8*)(hb + 32 + quad * 8);

    const bf16_t* Wt[3] = {whqT, whkT, whvT};
    const float*  Bb[3] = {bhq, bhk, bhv};
    f32x4 zf = {0.f, 0.f, 0.f, 0.f};
#pragma unroll
    for (int m3 = 0; m3 < 3; m3++) {
#pragma unroll
        for (int nf = 0; nf < 4; nf++) {
            f32x4 acc = zf;
            bf16x8 wb0 = *(const bf16x8*)(Wt[m3] + (nf * 16 + lane15) * 64 + quad * 8);
            bf16x8 wb1 = *(const bf16x8*)(Wt[m3] + (nf * 16 + lane15) * 64 + 32 + quad * 8);
            acc = __builtin_amdgcn_mfma_f32_16x16x32_bf16(ha0, wb0, acc, 0, 0, 0);
            acc = __builtin_amdgcn_mfma_f32_16x16x32_bf16(ha1, wb1, acc, 0, 0, 0);
            float bias = Bb[m3][nf * 16 + lane15];
#pragma unroll
            for (int r = 0; r < 4; r++) {
                float v = acc[r] + bias;
                if (m3 == 0) v *= 0.125f;   // fold inter scale into Qh (exact)
                if (m3 == 2) VhT[(nf * 16 + lane15) * 32 + quad * 4 + r] = (bf16_t)v;
                else if (m3 == 0) Qh[(quad * 4 + r) * 64 + nf * 16 + lane15] = (bf16_t)v;
                else Kh[(quad * 4 + r) * 64 + nf * 16 + lane15] = (bf16_t)v;
            }
        }
    }
    __syncthreads();

    bf16x8 qa0 = *(const bf16x8*)(Qh + lane15 * 64 + quad * 8);
    bf16x8 qa1 = *(const bf16x8*)(Qh + lane15 * 64 + 32 + quad * 8);
    bf16x8 kb0 = *(const bf16x8*)(Kh + lane15 * 64 + quad * 8);
    bf16x8 kb1 = *(const bf16x8*)(Kh + lane15 * 64 + 32 + quad * 8);
    f32x4 s = zf;
    s = __builtin_amdgcn_mfma_f32_16x16x32_bf16(qa0, kb0, s, 0, 0, 0);
    s = __builtin_amdgcn_mfma_f32_16x16x32_bf16(qa1, kb1, s, 0, 0, 0);
#pragma unroll
    for (int r = 0; r < 4; r++) {
        float v = s[r];
        float mx = v;
        mx = fmaxf(mx, __shfl_xor(mx, 1));
        mx = fmaxf(mx, __shfl_xor(mx, 2));
        mx = fmaxf(mx, __shfl_xor(mx, 4));
        mx = fmaxf(mx, __shfl_xor(mx, 8));
        float pv = __expf(v - mx);
        float sm = pv;
        sm += __shfl_xor(sm, 1);
        sm += __shfl_xor(sm, 2);
        sm += __shfl_xor(sm, 4);
        sm += __shfl_xor(sm, 8);
        P16[(quad * 4 + r) * 32 + lane15] = (bf16_t)(pv / sm);
    }
    __syncthreads();

    bf16x8 pa = *(const bf16x8*)(P16 + lane15 * 32 + quad * 8);
    bf16_t* outp = concat + (size_t)p * 1024;
#pragma unroll
    for (int df = 0; df < 4; df++) {
        bf16x8 vb = *(const bf16x8*)(VhT + (df * 16 + lane15) * 32 + quad * 8);
        f32x4 mix = zf;
        mix = __builtin_amdgcn_mfma_f32_16x16x32_bf16(pa, vb, mix, 0, 0, 0);
#pragma unroll
        for (int r = 0; r < 4; r++)
            outp[(quad * 4 + r) * 64 + df * 16 + lane15] = (bf16_t)mix[r];
    }
}

// ---------------------------------------------------------------------------
extern "C" void kernel_launch(void* const* d_in, const int* in_sizes, int n_in,
                              void* d_out, int out_size, void* d_ws, size_t ws_size,
                              hipStream_t stream)
{
    // Reference dtypes: all float tensors are float32; mask is int32.
    const float* q_in = (const float*)d_in[0];
    const float* k_in = (const float*)d_in[1];
    const float* v_in = (const float*)d_in[2];
    const int*   mask = (const int*)d_in[3];
    const float* wq = (const float*)d_in[4];
    const float* bq = (const float*)d_in[5];
    const float* wk = (const float*)d_in[6];
    const float* bk = (const float*)d_in[7];
    const float* wv = (const float*)d_in[8];
    const float* bv = (const float*)d_in[9];
    const float* wo = (const float*)d_in[10];
    const float* bo = (const float*)d_in[11];
    const float* whq = (const float*)d_in[12];
    const float* bhq = (const float*)d_in[13];
    const float* whk = (const float*)d_in[14];
    const float* bhk = (const float*)d_in[15];
    const float* whv = (const float*)d_in[16];
    const float* bhv = (const float*)d_in[17];
    // d_in[18]/d_in[19] (who/bho) are unused by the reference forward.
    float* out = (float*)d_out;         // [4096][1024] f32 = 16 MB

    // Workspace: EXACTLY 24 MB used.
    //   ws[0,8)MB   Q   (bf16 [B,H,L,DK])  -> reused as `concat` after flash
    //   ws[8,16)MB  K   (bf16 [B,H,L,DK])  -> reused as woT/whqT/... after flash
    //   ws[16,24)MB Vt  (bf16 [B,H,DK,L])
    // d_out doubles as scratch before its final write:
    //   d_out[0,8)MB   attn (bf16) during flash->interhead
    //   d_out[8,14)MB  wqkvT (bf16) during transpose->gemm_qkv
    char* ws = (char*)d_ws;
    bf16_t* qkvb  = (bf16_t*)ws;                       // 24 MB: Q|K|Vt
    bf16_t* concat = qkvb;                             // Q region, post-flash
    bf16_t* woT   = (bf16_t*)(ws + 8u * 1024 * 1024);  // K region, post-flash
    bf16_t* whqT  = (bf16_t*)(ws + 10u * 1024 * 1024);
    bf16_t* whkT  = whqT + 4096;
    bf16_t* whvT  = whqT + 8192;
    bf16_t* attnb = (bf16_t*)d_out;                    // 8 MB bf16 in d_out
    bf16_t* wqkvT = (bf16_t*)((char*)d_out + 8u * 1024 * 1024);  // 6 MB bf16

    // Phase 1: weights -> bf16 transposed (in d_out), QKV projections
    transpose_qkvw_kernel<<<dim3(16, 16, 3), 256, 0, stream>>>(wq, wk, wv, wqkvT);
    gemm_qkv_kernel<<<dim3(8, 32, 3), 256, 0, stream>>>(q_in, k_in, v_in, wqkvT, bq, bk, bv, qkvb);
    // Phase 2: flash attention -> attn (overwrites d_out[0,8MB))
    flash_kernel<<<dim3(32, 32), 256, 0, stream>>>(qkvb, mask, attnb);
    // Phase 3: K region now dead -> stage small transposed weights there
    transpose_one_kernel<<<dim3(16, 16), 256, 0, stream>>>(wo, woT);
    transpose_small_kernel<<<3, 256, 0, stream>>>(whq, whk, whv, whqT, whkT, whvT);
    interhead_kernel<<<1024, 256, 0, stream>>>(attnb, whqT, bhq, whkT, bhk, whvT, bhv, concat);
    // Phase 4: output projection -> f32 d_out (overwrites attn scratch)
    gemm_out_kernel<<<dim3(8, 32), 256, 0, stream>>>(concat, woT, bo, out);
    (void)in_sizes; (void)n_in; (void)out_size; (void)ws_size;
}

// Round 4
// 381.027 us; speedup vs baseline: 1.0715x; 1.0715x over previous
//
#include <hip/hip_runtime.h>
#include <hip/hip_bf16.h>

typedef __bf16 bf16_t;
typedef __bf16 bf16x8 __attribute__((ext_vector_type(8)));
typedef float f32x4 __attribute__((ext_vector_type(4)));

// ---------------------------------------------------------------------------
// Weight transposes with f32 -> bf16 convert: W[din][dout] -> WT[dout][din]
// ---------------------------------------------------------------------------
__global__ void transpose_qkvw_kernel(const float* __restrict__ wq, const float* __restrict__ wk,
                                      const float* __restrict__ wv, bf16_t* __restrict__ wqkvT)
{
    __shared__ bf16_t tile[64][65];
    int z = blockIdx.z;
    const float* src = (z == 0) ? wq : (z == 1) ? wk : wv;
    bf16_t* dst = wqkvT + (size_t)z * 1048576;
    int rB = blockIdx.y * 64, cB = blockIdx.x * 64;
    int t = threadIdx.x;
#pragma unroll
    for (int i = 0; i < 16; i++) {
        int e = t + i * 256; int r = e >> 6, c = e & 63;
        tile[r][c] = (bf16_t)src[(size_t)(rB + r) * 1024 + cB + c];
    }
    __syncthreads();
#pragma unroll
    for (int i = 0; i < 16; i++) {
        int e = t + i * 256; int r = e >> 6, c = e & 63;
        dst[(size_t)(cB + r) * 1024 + rB + c] = tile[c][r];
    }
}

__global__ void transpose_one_kernel(const float* __restrict__ src, bf16_t* __restrict__ dst)
{
    __shared__ bf16_t tile[64][65];
    int rB = blockIdx.y * 64, cB = blockIdx.x * 64;
    int t = threadIdx.x;
#pragma unroll
    for (int i = 0; i < 16; i++) {
        int e = t + i * 256; int r = e >> 6, c = e & 63;
        tile[r][c] = (bf16_t)src[(size_t)(rB + r) * 1024 + cB + c];
    }
    __syncthreads();
#pragma unroll
    for (int i = 0; i < 16; i++) {
        int e = t + i * 256; int r = e >> 6, c = e & 63;
        dst[(size_t)(cB + r) * 1024 + rB + c] = tile[c][r];
    }
}

__global__ void transpose_small_kernel(const float* __restrict__ s0, const float* __restrict__ s1,
                                       const float* __restrict__ s2,
                                       bf16_t* __restrict__ d0, bf16_t* __restrict__ d1, bf16_t* __restrict__ d2)
{
    int z = blockIdx.x;
    const float* src = (z == 0) ? s0 : (z == 1) ? s1 : s2;
    bf16_t* dst = (z == 0) ? d0 : (z == 1) ? d1 : d2;
    int t = threadIdx.x;
#pragma unroll
    for (int i = 0; i < 16; i++) {
        int e = t + i * 256; int r = e >> 6, c = e & 63;
        dst[c * 64 + r] = (bf16_t)src[r * 64 + c];
    }
}

// ---------------------------------------------------------------------------
// Mask pre-scan: flags[b*1024 + qt*32 + kt] = 1 iff whole 64x64 tile nonzero
// ---------------------------------------------------------------------------
__global__ void maskflags_kernel(const int* __restrict__ mask, int* __restrict__ flags)
{
    int tile = blockIdx.x;              // b*1024 + qt*32 + kt
    int b = tile >> 10, qt = (tile >> 5) & 31, kt = tile & 31;
    int ok = 1;
#pragma unroll
    for (int i = 0; i < 16; i++) {
        int e = threadIdx.x + i * 256; int r = e >> 6, c = e & 63;
        ok &= (mask[((size_t)b * 2048 + qt * 64 + r) * 2048 + kt * 64 + c] != 0) ? 1 : 0;
    }
    ok = __syncthreads_and(ok);
    if (threadIdx.x == 0) flags[tile] = ok;
}

// ---------------------------------------------------------------------------
// QKV GEMM: A f32 [4096][1024], Bt (weights^T) bf16 [1024][1024].
// 128x128 C-tile, BK=32, 4 waves, 4x4 16x16x32 bf16 MFMA frags.
// LDS stride padded 32->40 bf16 to break 8-way bank aliasing.
// Q/K -> [B,H,L,DK]; V -> [B,H,DK,L]
// ---------------------------------------------------------------------------
#define GS 40   // GEMM LDS row stride (bf16 elems) for a 32-wide K tile

__global__ __launch_bounds__(256, 2) void gemm_qkv_kernel(
    const float* __restrict__ Aq, const float* __restrict__ Ak, const float* __restrict__ Av,
    const bf16_t* __restrict__ WT,
    const float* __restrict__ bq, const float* __restrict__ bk, const float* __restrict__ bv,
    bf16_t* __restrict__ outbase)
{
    __shared__ bf16_t As[128 * GS];
    __shared__ bf16_t Bs[128 * GS];
    const int z = blockIdx.z;
    const float* A    = (z == 0) ? Aq : (z == 1) ? Ak : Av;
    const bf16_t* Bt  = WT + (size_t)z * 1048576;
    const float* bia  = (z == 0) ? bq : (z == 1) ? bk : bv;
    bf16_t* out = outbase + (size_t)z * 4194304;

    const int t = threadIdx.x;
    const int w = t >> 6, lane = t & 63;
    const int lane15 = lane & 15, quad = lane >> 4;
    const int wr = w >> 1, wc = w & 1;
    const int rowBase = blockIdx.y * 128, colBase = blockIdx.x * 128;

    // A staging: thread t -> row t>>1, cols (t&1)*16 + [0,16)  (f32 -> bf16)
    const int ar = t >> 1, ac = (t & 1) * 16;
    // B staging: elements e0/e1 of [128][32] bf16 tile
    const int e0 = t * 8, e1 = (256 + t) * 8;
    const int r0 = e0 >> 5, c0 = e0 & 31;
    const int r1 = e1 >> 5, c1 = e1 & 31;

    f32x4 acc[4][4];
    f32x4 zf = {0.f, 0.f, 0.f, 0.f};
#pragma unroll
    for (int i = 0; i < 4; i++)
#pragma unroll
        for (int j = 0; j < 4; j++) acc[i][j] = zf;

    for (int k0 = 0; k0 < 1024; k0 += 32) {
        const float4* ap = (const float4*)(A + (size_t)(rowBase + ar) * 1024 + k0 + ac);
        float4 af4[4];
#pragma unroll
        for (int i = 0; i < 4; i++) af4[i] = ap[i];
        bf16x8 b0 = *(const bf16x8*)(Bt + (size_t)(colBase + r0) * 1024 + k0 + c0);
        bf16x8 b1 = *(const bf16x8*)(Bt + (size_t)(colBase + r1) * 1024 + k0 + c1);
        bf16x8 av0, av1;
#pragma unroll
        for (int i = 0; i < 4; i++) {
            bf16x8& dstv = (i < 2) ? av0 : av1;
            int base = (i & 1) * 4;
            dstv[base + 0] = (bf16_t)af4[i].x; dstv[base + 1] = (bf16_t)af4[i].y;
            dstv[base + 2] = (bf16_t)af4[i].z; dstv[base + 3] = (bf16_t)af4[i].w;
        }
        *(bf16x8*)(As + ar * GS + ac) = av0;
        *(bf16x8*)(As + ar * GS + ac + 8) = av1;
        *(bf16x8*)(Bs + r0 * GS + c0) = b0;
        *(bf16x8*)(Bs + r1 * GS + c1) = b1;
        __syncthreads();
        bf16x8 afr[4], bfr[4];
#pragma unroll
        for (int mi = 0; mi < 4; mi++)
            afr[mi] = *(const bf16x8*)(As + (wr * 64 + mi * 16 + lane15) * GS + quad * 8);
#pragma unroll
        for (int ni = 0; ni < 4; ni++)
            bfr[ni] = *(const bf16x8*)(Bs + (wc * 64 + ni * 16 + lane15) * GS + quad * 8);
#pragma unroll
        for (int mi = 0; mi < 4; mi++)
#pragma unroll
            for (int ni = 0; ni < 4; ni++)
                acc[mi][ni] = __builtin_amdgcn_mfma_f32_16x16x32_bf16(afr[mi], bfr[ni], acc[mi][ni], 0, 0, 0);
        __syncthreads();
    }

#pragma unroll
    for (int ni = 0; ni < 4; ni++) {
        int col = colBase + wc * 64 + ni * 16 + lane15;   // dout
        float bias = bia[col];
        int h = col >> 6, dk = col & 63;
#pragma unroll
        for (int mi = 0; mi < 4; mi++) {
#pragma unroll
            for (int r = 0; r < 4; r++) {
                int row = rowBase + wr * 64 + mi * 16 + quad * 4 + r;
                int b = row >> 11, l = row & 2047;
                float v = acc[mi][ni][r] + bias;
                size_t dst = (z < 2) ? ((((size_t)(b * 16 + h)) * 2048 + l) * 64 + dk)
                                     : ((((size_t)(b * 16 + h)) * 64 + dk) * 2048 + l);
                out[dst] = (bf16_t)v;
            }
        }
    }
}

// ---------------------------------------------------------------------------
// Output projection: A (concat) bf16 [4096][1024], Bt (woT) bf16, out f32.
// ---------------------------------------------------------------------------
__global__ __launch_bounds__(256, 2) void gemm_out_kernel(
    const bf16_t* __restrict__ A, const bf16_t* __restrict__ Bt,
    const float* __restrict__ bia, float* __restrict__ out)
{
    __shared__ bf16_t As[128 * GS];
    __shared__ bf16_t Bs[128 * GS];
    const int t = threadIdx.x;
    const int w = t >> 6, lane = t & 63;
    const int lane15 = lane & 15, quad = lane >> 4;
    const int wr = w >> 1, wc = w & 1;
    const int rowBase = blockIdx.y * 128, colBase = blockIdx.x * 128;
    const int e0 = t * 8, e1 = (256 + t) * 8;
    const int r0 = e0 >> 5, c0 = e0 & 31;
    const int r1 = e1 >> 5, c1 = e1 & 31;

    f32x4 acc[4][4];
    f32x4 zf = {0.f, 0.f, 0.f, 0.f};
#pragma unroll
    for (int i = 0; i < 4; i++)
#pragma unroll
        for (int j = 0; j < 4; j++) acc[i][j] = zf;

    for (int k0 = 0; k0 < 1024; k0 += 32) {
        bf16x8 a0 = *(const bf16x8*)(A  + (size_t)(rowBase + r0) * 1024 + k0 + c0);
        bf16x8 a1 = *(const bf16x8*)(A  + (size_t)(rowBase + r1) * 1024 + k0 + c1);
        bf16x8 b0 = *(const bf16x8*)(Bt + (size_t)(colBase + r0) * 1024 + k0 + c0);
        bf16x8 b1 = *(const bf16x8*)(Bt + (size_t)(colBase + r1) * 1024 + k0 + c1);
        *(bf16x8*)(As + r0 * GS + c0) = a0;
        *(bf16x8*)(As + r1 * GS + c1) = a1;
        *(bf16x8*)(Bs + r0 * GS + c0) = b0;
        *(bf16x8*)(Bs + r1 * GS + c1) = b1;
        __syncthreads();
        bf16x8 afr[4], bfr[4];
#pragma unroll
        for (int mi = 0; mi < 4; mi++)
            afr[mi] = *(const bf16x8*)(As + (wr * 64 + mi * 16 + lane15) * GS + quad * 8);
#pragma unroll
        for (int ni = 0; ni < 4; ni++)
            bfr[ni] = *(const bf16x8*)(Bs + (wc * 64 + ni * 16 + lane15) * GS + quad * 8);
#pragma unroll
        for (int mi = 0; mi < 4; mi++)
#pragma unroll
            for (int ni = 0; ni < 4; ni++)
                acc[mi][ni] = __builtin_amdgcn_mfma_f32_16x16x32_bf16(afr[mi], bfr[ni], acc[mi][ni], 0, 0, 0);
        __syncthreads();
    }

#pragma unroll
    for (int ni = 0; ni < 4; ni++) {
        int col = colBase + wc * 64 + ni * 16 + lane15;
        float bias = bia[col];
#pragma unroll
        for (int mi = 0; mi < 4; mi++) {
#pragma unroll
            for (int r = 0; r < 4; r++) {
                int row = rowBase + wr * 64 + mi * 16 + quad * 4 + r;
                out[(size_t)row * 1024 + col] = acc[mi][ni][r] + bias;
            }
        }
    }
}

// ---------------------------------------------------------------------------
// Flash attention: one block per (qtile64, bh); 4 waves x 16 q-rows.
// Q,K bf16 [B,H,L,DK]; V bf16 [B,H,DK,L]. scale=0.125 on Q (exact pow2).
// LDS stride padded 64->72 to break 16-way bank conflicts on B-frag reads.
// attn written [B,L,H,DK] for contiguous interhead loads.
// ---------------------------------------------------------------------------
#define FS 72   // flash LDS row stride (bf16 elems) for 64-wide tiles

__global__ __launch_bounds__(256, 2) void flash_kernel(
    const bf16_t* __restrict__ QKV, const int* __restrict__ mask,
    const int* __restrict__ flags, bf16_t* __restrict__ attnout)
{
    __shared__ bf16_t Ks[64 * FS];
    __shared__ bf16_t Vs[64 * FS];
    __shared__ bf16_t Ps[4 * 16 * FS];
    const int t = threadIdx.x, w = t >> 6, lane = t & 63;
    const int lane15 = lane & 15, quad = lane >> 4;
    const int qt = blockIdx.x, bh = blockIdx.y;
    const int b = bh >> 4, h = bh & 15;
    const bf16_t* Q  = QKV;
    const bf16_t* K  = QKV + 4194304;
    const bf16_t* Vt = QKV + 8388608;
    const int qrow0 = qt * 64 + w * 16;

    const bf16_t* qb = Q + ((size_t)bh * 2048 + qrow0 + lane15) * 64;
    bf16x8 aq0 = *(const bf16x8*)(qb + quad * 8);
    bf16x8 aq1 = *(const bf16x8*)(qb + 32 + quad * 8);
#pragma unroll
    for (int j = 0; j < 8; j++) {       // exact: *2^-3
        aq0[j] = (bf16_t)((float)aq0[j] * 0.125f);
        aq1[j] = (bf16_t)((float)aq1[j] * 0.125f);
    }

    f32x4 o[4];
    f32x4 zf = {0.f, 0.f, 0.f, 0.f};
#pragma unroll
    for (int df = 0; df < 4; df++) o[df] = zf;
    float m_i[4], l_i[4];
#pragma unroll
    for (int r = 0; r < 4; r++) { m_i[r] = -1e30f; l_i[r] = 0.f; }
    bf16_t* Pw = Ps + w * 16 * FS;

    const int e0 = t * 8, e1 = (256 + t) * 8;
    const int kr0 = e0 >> 6, kc0 = e0 & 63, kr1 = e1 >> 6, kc1 = e1 & 63;
    const int* flagrow = flags + (b * 32 + qt) * 32;

    for (int kt = 0; kt < 32; kt++) {
        bf16x8 k0v = *(const bf16x8*)(K  + ((size_t)bh * 2048 + kt * 64 + kr0) * 64 + kc0);
        bf16x8 k1v = *(const bf16x8*)(K  + ((size_t)bh * 2048 + kt * 64 + kr1) * 64 + kc1);
        bf16x8 v0v = *(const bf16x8*)(Vt + ((size_t)bh * 64 + kr0) * 2048 + kt * 64 + kc0);
        bf16x8 v1v = *(const bf16x8*)(Vt + ((size_t)bh * 64 + kr1) * 2048 + kt * 64 + kc1);
        *(bf16x8*)(Ks + kr0 * FS + kc0) = k0v;
        *(bf16x8*)(Ks + kr1 * FS + kc1) = k1v;
        *(bf16x8*)(Vs + kr0 * FS + kc0) = v0v;
        *(bf16x8*)(Vs + kr1 * FS + kc1) = v1v;
        __syncthreads();

        f32x4 sf[4];
#pragma unroll
        for (int nf = 0; nf < 4; nf++) {
            f32x4 a = zf;
            bf16x8 kb0 = *(const bf16x8*)(Ks + (nf * 16 + lane15) * FS + quad * 8);
            bf16x8 kb1 = *(const bf16x8*)(Ks + (nf * 16 + lane15) * FS + 32 + quad * 8);
            a = __builtin_amdgcn_mfma_f32_16x16x32_bf16(aq0, kb0, a, 0, 0, 0);
            a = __builtin_amdgcn_mfma_f32_16x16x32_bf16(aq1, kb1, a, 0, 0, 0);
            sf[nf] = a;
        }
        if (!flagrow[kt]) {   // slow path: per-element mask (never taken if all-ones)
#pragma unroll
            for (int nf = 0; nf < 4; nf++)
#pragma unroll
                for (int r = 0; r < 4; r++) {
                    int qrow = qrow0 + quad * 4 + r;
                    int kpos = kt * 64 + nf * 16 + lane15;
                    if (mask[((size_t)b * 2048 + qrow) * 2048 + kpos] == 0)
                        sf[nf][r] = -1e30f;
                }
        }
        float alpha[4], pf[4][4];
#pragma unroll
        for (int r = 0; r < 4; r++) {
            float mx = fmaxf(fmaxf(sf[0][r], sf[1][r]), fmaxf(sf[2][r], sf[3][r]));
            mx = fmaxf(mx, __shfl_xor(mx, 1));
            mx = fmaxf(mx, __shfl_xor(mx, 2));
            mx = fmaxf(mx, __shfl_xor(mx, 4));
            mx = fmaxf(mx, __shfl_xor(mx, 8));
            float mn = fmaxf(m_i[r], mx);
            alpha[r] = __expf(m_i[r] - mn);
            m_i[r] = mn;
            float rs = 0.f;
#pragma unroll
            for (int nf = 0; nf < 4; nf++) { float pv = __expf(sf[nf][r] - mn); pf[nf][r] = pv; rs += pv; }
            rs += __shfl_xor(rs, 1);
            rs += __shfl_xor(rs, 2);
            rs += __shfl_xor(rs, 4);
            rs += __shfl_xor(rs, 8);
            l_i[r] = l_i[r] * alpha[r] + rs;
        }
        // P: C-layout -> A-layout via wave-private LDS (no barrier needed)
#pragma unroll
        for (int nf = 0; nf < 4; nf++)
#pragma unroll
            for (int r = 0; r < 4; r++)
                Pw[(quad * 4 + r) * FS + nf * 16 + lane15] = (bf16_t)pf[nf][r];

        bf16x8 pa0 = *(const bf16x8*)(Pw + lane15 * FS + quad * 8);
        bf16x8 pa1 = *(const bf16x8*)(Pw + lane15 * FS + 32 + quad * 8);
#pragma unroll
        for (int df = 0; df < 4; df++) {
            f32x4 oo = o[df];
#pragma unroll
            for (int r = 0; r < 4; r++) oo[r] *= alpha[r];
            bf16x8 vb0 = *(const bf16x8*)(Vs + (df * 16 + lane15) * FS + quad * 8);
            bf16x8 vb1 = *(const bf16x8*)(Vs + (df * 16 + lane15) * FS + 32 + quad * 8);
            oo = __builtin_amdgcn_mfma_f32_16x16x32_bf16(pa0, vb0, oo, 0, 0, 0);
            oo = __builtin_amdgcn_mfma_f32_16x16x32_bf16(pa1, vb1, oo, 0, 0, 0);
            o[df] = oo;
        }
        __syncthreads();   // all waves done reading Ks/Vs before restage
    }
    // attn out: [B,L,H,DK]
#pragma unroll
    for (int df = 0; df < 4; df++)
#pragma unroll
        for (int r = 0; r < 4; r++) {
            float v = o[df][r] / l_i[r];
            size_t row = (size_t)b * 2048 + qrow0 + quad * 4 + r;
            attnout[(row * 16 + h) * 64 + df * 16 + lane15] = (bf16_t)v;
        }
}

// ---------------------------------------------------------------------------
// Inter-head attention: one wave per position (b,l). attn is [B,L,H,DK].
// ---------------------------------------------------------------------------
__global__ __launch_bounds__(256, 2) void interhead_kernel(
    const bf16_t* __restrict__ attn,
    const bf16_t* __restrict__ whqT, const float* __restrict__ bhq,
    const bf16_t* __restrict__ whkT, const float* __restrict__ bhk,
    const bf16_t* __restrict__ whvT, const float* __restrict__ bhv,
    bf16_t* __restrict__ concat)
{
    __shared__ bf16_t lds[4 * 4608];
    const int t = threadIdx.x, w = t >> 6, lane = t & 63;
    const int lane15 = lane & 15, quad = lane >> 4;
    bf16_t* Qh  = lds + w * 4608;   // [16][64]
    bf16_t* Kh  = Qh + 1024;        // [16][64]
    bf16_t* VhT = Kh + 1024;        // [64][32] (k-padded)
    bf16_t* P16 = VhT + 2048;       // [16][32] (k-padded)
    const int p = blockIdx.x * 4 + w;

    bf16x8 z8 = {(bf16_t)0.f, (bf16_t)0.f, (bf16_t)0.f, (bf16_t)0.f,
                 (bf16_t)0.f, (bf16_t)0.f, (bf16_t)0.f, (bf16_t)0.f};
    ((bf16x8*)P16)[lane] = z8;
#pragma unroll
    for (int i = 0; i < 4; i++) ((bf16x8*)VhT)[i * 64 + lane] = z8;

    // heads[g][d] for this position: contiguous 1024 bf16 per wave
    const bf16_t* hb = attn + ((size_t)p * 16 + lane15) * 64;
    bf16x8 ha0 = *(const bf16x8*)(hb + quad * 8);
    bf16x8 ha1 = *(const bf16x8*)(hb + 32 + quad * 8);

    const bf16_t* Wt[3] = {whqT, whkT, whvT};
    const float*  Bb[3] = {bhq, bhk, bhv};
    f32x4 zf = {0.f, 0.f, 0.f, 0.f};
#pragma unroll
    for (int m3 = 0; m3 < 3; m3++) {
#pragma unroll
        for (int nf = 0; nf < 4; nf++) {
            f32x4 acc = zf;
            bf16x8 wb0 = *(const bf16x8*)(Wt[m3] + (nf * 16 + lane15) * 64 + quad * 8);
            bf16x8 wb1 = *(const bf16x8*)(Wt[m3] + (nf * 16 + lane15) * 64 + 32 + quad * 8);
            acc = __builtin_amdgcn_mfma_f32_16x16x32_bf16(ha0, wb0, acc, 0, 0, 0);
            acc = __builtin_amdgcn_mfma_f32_16x16x32_bf16(ha1, wb1, acc, 0, 0, 0);
            float bias = Bb[m3][nf * 16 + lane15];
#pragma unroll
            for (int r = 0; r < 4; r++) {
                float v = acc[r] + bias;
                if (m3 == 0) v *= 0.125f;   // fold inter scale into Qh (exact)
                if (m3 == 2) VhT[(nf * 16 + lane15) * 32 + quad * 4 + r] = (bf16_t)v;
                else if (m3 == 0) Qh[(quad * 4 + r) * 64 + nf * 16 + lane15] = (bf16_t)v;
                else Kh[(quad * 4 + r) * 64 + nf * 16 + lane15] = (bf16_t)v;
            }
        }
    }
    __syncthreads();

    bf16x8 qa0 = *(const bf16x8*)(Qh + lane15 * 64 + quad * 8);
    bf16x8 qa1 = *(const bf16x8*)(Qh + lane15 * 64 + 32 + quad * 8);
    bf16x8 kb0 = *(const bf16x8*)(Kh + lane15 * 64 + quad * 8);
    bf16x8 kb1 = *(const bf16x8*)(Kh + lane15 * 64 + 32 + quad * 8);
    f32x4 s = zf;
    s = __builtin_amdgcn_mfma_f32_16x16x32_bf16(qa0, kb0, s, 0, 0, 0);
    s = __builtin_amdgcn_mfma_f32_16x16x32_bf16(qa1, kb1, s, 0, 0, 0);
#pragma unroll
    for (int r = 0; r < 4; r++) {
        float v = s[r];
        float mx = v;
        mx = fmaxf(mx, __shfl_xor(mx, 1));
        mx = fmaxf(mx, __shfl_xor(mx, 2));
        mx = fmaxf(mx, __shfl_xor(mx, 4));
        mx = fmaxf(mx, __shfl_xor(mx, 8));
        float pv = __expf(v - mx);
        float sm = pv;
        sm += __shfl_xor(sm, 1);
        sm += __shfl_xor(sm, 2);
        sm += __shfl_xor(sm, 4);
        sm += __shfl_xor(sm, 8);
        P16[(quad * 4 + r) * 32 + lane15] = (bf16_t)(pv / sm);
    }
    __syncthreads();

    bf16x8 pa = *(const bf16x8*)(P16 + lane15 * 32 + quad * 8);
    bf16_t* outp = concat + (size_t)p * 1024;
#pragma unroll
    for (int df = 0; df < 4; df++) {
        bf16x8 vb = *(const bf16x8*)(VhT + (df * 16 + lane15) * 32 + quad * 8);
        f32x4 mix = zf;
        mix = __builtin_amdgcn_mfma_f32_16x16x32_bf16(pa, vb, mix, 0, 0, 0);
#pragma unroll
        for (int r = 0; r < 4; r++)
            outp[(quad * 4 + r) * 64 + df * 16 + lane15] = (bf16_t)mix[r];
    }
}

// ---------------------------------------------------------------------------
extern "C" void kernel_launch(void* const* d_in, const int* in_sizes, int n_in,
                              void* d_out, int out_size, void* d_ws, size_t ws_size,
                              hipStream_t stream)
{
    const float* q_in = (const float*)d_in[0];
    const float* k_in = (const float*)d_in[1];
    const float* v_in = (const float*)d_in[2];
    const int*   mask = (const int*)d_in[3];
    const float* wq = (const float*)d_in[4];
    const float* bq = (const float*)d_in[5];
    const float* wk = (const float*)d_in[6];
    const float* bk = (const float*)d_in[7];
    const float* wv = (const float*)d_in[8];
    const float* bv = (const float*)d_in[9];
    const float* wo = (const float*)d_in[10];
    const float* bo = (const float*)d_in[11];
    const float* whq = (const float*)d_in[12];
    const float* bhq = (const float*)d_in[13];
    const float* whk = (const float*)d_in[14];
    const float* bhk = (const float*)d_in[15];
    const float* whv = (const float*)d_in[16];
    const float* bhv = (const float*)d_in[17];
    float* out = (float*)d_out;         // [4096][1024] f32 = 16 MB

    // Workspace: exactly 24 MB of d_ws.
    //   ws[0,8)MB   Q  (bf16 [B,H,L,DK])  -> reused as `concat` after flash
    //   ws[8,16)MB  K  (bf16 [B,H,L,DK])  -> reused as woT/whqT/... after flash
    //   ws[16,24)MB Vt (bf16 [B,H,DK,L])
    // d_out doubles as scratch before its final f32 write:
    //   d_out[0,8)MB   attn (bf16 [B,L,H,DK])
    //   d_out[8,14)MB  wqkvT (bf16)
    //   d_out[14,14+8K) mask tile flags
    char* ws = (char*)d_ws;
    bf16_t* qkvb  = (bf16_t*)ws;
    bf16_t* concat = qkvb;
    bf16_t* woT   = (bf16_t*)(ws + 8u * 1024 * 1024);
    bf16_t* whqT  = (bf16_t*)(ws + 10u * 1024 * 1024);
    bf16_t* whkT  = whqT + 4096;
    bf16_t* whvT  = whqT + 8192;
    bf16_t* attnb = (bf16_t*)d_out;
    bf16_t* wqkvT = (bf16_t*)((char*)d_out + 8u * 1024 * 1024);
    int*    flags = (int*)((char*)d_out + 14u * 1024 * 1024);

    maskflags_kernel<<<2048, 256, 0, stream>>>(mask, flags);
    transpose_qkvw_kernel<<<dim3(16, 16, 3), 256, 0, stream>>>(wq, wk, wv, wqkvT);
    gemm_qkv_kernel<<<dim3(8, 32, 3), 256, 0, stream>>>(q_in, k_in, v_in, wqkvT, bq, bk, bv, qkvb);
    flash_kernel<<<dim3(32, 32), 256, 0, stream>>>(qkvb, mask, flags, attnb);
    transpose_one_kernel<<<dim3(16, 16), 256, 0, stream>>>(wo, woT);
    transpose_small_kernel<<<3, 256, 0, stream>>>(whq, whk, whv, whqT, whkT, whvT);
    interhead_kernel<<<1024, 256, 0, stream>>>(attnb, whqT, bhq, whkT, bhk, whvT, bhv, concat);
    gemm_out_kernel<<<dim3(8, 32), 256, 0, stream>>>(concat, woT, bo, out);
    (void)in_sizes; (void)n_in; (void)out_size; (void)ws_size;
}

// Round 5
// 352.316 us; speedup vs baseline: 1.1588x; 1.0815x over previous
//
#include <hip/hip_runtime.h>
#include <hip/hip_bf16.h>

typedef __bf16 bf16_t;
typedef __bf16 bf16x8 __attribute__((ext_vector_type(8)));
typedef float f32x4 __attribute__((ext_vector_type(4)));

// ---------------------------------------------------------------------------
// Weight transposes with f32 -> bf16 convert: W[din][dout] -> WT[dout][din]
// ---------------------------------------------------------------------------
__global__ void transpose_qkvw_kernel(const float* __restrict__ wq, const float* __restrict__ wk,
                                      const float* __restrict__ wv, bf16_t* __restrict__ wqkvT)
{
    __shared__ bf16_t tile[64][65];
    int z = blockIdx.z;
    const float* src = (z == 0) ? wq : (z == 1) ? wk : wv;
    bf16_t* dst = wqkvT + (size_t)z * 1048576;
    int rB = blockIdx.y * 64, cB = blockIdx.x * 64;
    int t = threadIdx.x;
#pragma unroll
    for (int i = 0; i < 16; i++) {
        int e = t + i * 256; int r = e >> 6, c = e & 63;
        tile[r][c] = (bf16_t)src[(size_t)(rB + r) * 1024 + cB + c];
    }
    __syncthreads();
#pragma unroll
    for (int i = 0; i < 16; i++) {
        int e = t + i * 256; int r = e >> 6, c = e & 63;
        dst[(size_t)(cB + r) * 1024 + rB + c] = tile[c][r];
    }
}

__global__ void transpose_one_kernel(const float* __restrict__ src, bf16_t* __restrict__ dst)
{
    __shared__ bf16_t tile[64][65];
    int rB = blockIdx.y * 64, cB = blockIdx.x * 64;
    int t = threadIdx.x;
#pragma unroll
    for (int i = 0; i < 16; i++) {
        int e = t + i * 256; int r = e >> 6, c = e & 63;
        tile[r][c] = (bf16_t)src[(size_t)(rB + r) * 1024 + cB + c];
    }
    __syncthreads();
#pragma unroll
    for (int i = 0; i < 16; i++) {
        int e = t + i * 256; int r = e >> 6, c = e & 63;
        dst[(size_t)(cB + r) * 1024 + rB + c] = tile[c][r];
    }
}

__global__ void transpose_small_kernel(const float* __restrict__ s0, const float* __restrict__ s1,
                                       const float* __restrict__ s2,
                                       bf16_t* __restrict__ d0, bf16_t* __restrict__ d1, bf16_t* __restrict__ d2)
{
    int z = blockIdx.x;
    const float* src = (z == 0) ? s0 : (z == 1) ? s1 : s2;
    bf16_t* dst = (z == 0) ? d0 : (z == 1) ? d1 : d2;
    int t = threadIdx.x;
#pragma unroll
    for (int i = 0; i < 16; i++) {
        int e = t + i * 256; int r = e >> 6, c = e & 63;
        dst[c * 64 + r] = (bf16_t)src[r * 64 + c];
    }
}

// ---------------------------------------------------------------------------
// Mask pre-scan: flags[b*1024 + qt*32 + kt] = 1 iff whole 64x64 tile nonzero
// ---------------------------------------------------------------------------
__global__ void maskflags_kernel(const int* __restrict__ mask, int* __restrict__ flags)
{
    int tile = blockIdx.x;              // b*1024 + qt*32 + kt
    int b = tile >> 10, qt = (tile >> 5) & 31, kt = tile & 31;
    int ok = 1;
#pragma unroll
    for (int i = 0; i < 16; i++) {
        int e = threadIdx.x + i * 256; int r = e >> 6, c = e & 63;
        ok &= (mask[((size_t)b * 2048 + qt * 64 + r) * 2048 + kt * 64 + c] != 0) ? 1 : 0;
    }
    ok = __syncthreads_and(ok);
    if (threadIdx.x == 0) flags[tile] = ok;
}

// ---------------------------------------------------------------------------
// QKV GEMM: A f32 [4096][1024], Bt (weights^T) bf16 [1024][1024].
// 128x128 C-tile, BK=32, 4 waves, 4x4 16x16x32 bf16 MFMA frags.
// ---------------------------------------------------------------------------
#define GS 40   // GEMM LDS row stride (bf16 elems) for a 32-wide K tile

__global__ __launch_bounds__(256, 2) void gemm_qkv_kernel(
    const float* __restrict__ Aq, const float* __restrict__ Ak, const float* __restrict__ Av,
    const bf16_t* __restrict__ WT,
    const float* __restrict__ bq, const float* __restrict__ bk, const float* __restrict__ bv,
    bf16_t* __restrict__ outbase)
{
    __shared__ bf16_t As[128 * GS];
    __shared__ bf16_t Bs[128 * GS];
    const int z = blockIdx.z;
    const float* A    = (z == 0) ? Aq : (z == 1) ? Ak : Av;
    const bf16_t* Bt  = WT + (size_t)z * 1048576;
    const float* bia  = (z == 0) ? bq : (z == 1) ? bk : bv;
    bf16_t* out = outbase + (size_t)z * 4194304;

    const int t = threadIdx.x;
    const int w = t >> 6, lane = t & 63;
    const int lane15 = lane & 15, quad = lane >> 4;
    const int wr = w >> 1, wc = w & 1;
    const int rowBase = blockIdx.y * 128, colBase = blockIdx.x * 128;

    const int ar = t >> 1, ac = (t & 1) * 16;
    const int e0 = t * 8, e1 = (256 + t) * 8;
    const int r0 = e0 >> 5, c0 = e0 & 31;
    const int r1 = e1 >> 5, c1 = e1 & 31;

    f32x4 acc[4][4];
    f32x4 zf = {0.f, 0.f, 0.f, 0.f};
#pragma unroll
    for (int i = 0; i < 4; i++)
#pragma unroll
        for (int j = 0; j < 4; j++) acc[i][j] = zf;

    for (int k0 = 0; k0 < 1024; k0 += 32) {
        const float4* ap = (const float4*)(A + (size_t)(rowBase + ar) * 1024 + k0 + ac);
        float4 af4[4];
#pragma unroll
        for (int i = 0; i < 4; i++) af4[i] = ap[i];
        bf16x8 b0 = *(const bf16x8*)(Bt + (size_t)(colBase + r0) * 1024 + k0 + c0);
        bf16x8 b1 = *(const bf16x8*)(Bt + (size_t)(colBase + r1) * 1024 + k0 + c1);
        bf16x8 av0, av1;
#pragma unroll
        for (int i = 0; i < 4; i++) {
            bf16x8& dstv = (i < 2) ? av0 : av1;
            int base = (i & 1) * 4;
            dstv[base + 0] = (bf16_t)af4[i].x; dstv[base + 1] = (bf16_t)af4[i].y;
            dstv[base + 2] = (bf16_t)af4[i].z; dstv[base + 3] = (bf16_t)af4[i].w;
        }
        *(bf16x8*)(As + ar * GS + ac) = av0;
        *(bf16x8*)(As + ar * GS + ac + 8) = av1;
        *(bf16x8*)(Bs + r0 * GS + c0) = b0;
        *(bf16x8*)(Bs + r1 * GS + c1) = b1;
        __syncthreads();
        bf16x8 afr[4], bfr[4];
#pragma unroll
        for (int mi = 0; mi < 4; mi++)
            afr[mi] = *(const bf16x8*)(As + (wr * 64 + mi * 16 + lane15) * GS + quad * 8);
#pragma unroll
        for (int ni = 0; ni < 4; ni++)
            bfr[ni] = *(const bf16x8*)(Bs + (wc * 64 + ni * 16 + lane15) * GS + quad * 8);
#pragma unroll
        for (int mi = 0; mi < 4; mi++)
#pragma unroll
            for (int ni = 0; ni < 4; ni++)
                acc[mi][ni] = __builtin_amdgcn_mfma_f32_16x16x32_bf16(afr[mi], bfr[ni], acc[mi][ni], 0, 0, 0);
        __syncthreads();
    }

#pragma unroll
    for (int ni = 0; ni < 4; ni++) {
        int col = colBase + wc * 64 + ni * 16 + lane15;   // dout
        float bias = bia[col];
        int h = col >> 6, dk = col & 63;
#pragma unroll
        for (int mi = 0; mi < 4; mi++) {
#pragma unroll
            for (int r = 0; r < 4; r++) {
                int row = rowBase + wr * 64 + mi * 16 + quad * 4 + r;
                int b = row >> 11, l = row & 2047;
                float v = acc[mi][ni][r] + bias;
                size_t dst = (z < 2) ? ((((size_t)(b * 16 + h)) * 2048 + l) * 64 + dk)
                                     : ((((size_t)(b * 16 + h)) * 64 + dk) * 2048 + l);
                out[dst] = (bf16_t)v;
            }
        }
    }
}

// ---------------------------------------------------------------------------
// Output projection: A (concat) bf16 [4096][1024], Bt (woT) bf16, out f32.
// ---------------------------------------------------------------------------
__global__ __launch_bounds__(256, 2) void gemm_out_kernel(
    const bf16_t* __restrict__ A, const bf16_t* __restrict__ Bt,
    const float* __restrict__ bia, float* __restrict__ out)
{
    __shared__ bf16_t As[128 * GS];
    __shared__ bf16_t Bs[128 * GS];
    const int t = threadIdx.x;
    const int w = t >> 6, lane = t & 63;
    const int lane15 = lane & 15, quad = lane >> 4;
    const int wr = w >> 1, wc = w & 1;
    const int rowBase = blockIdx.y * 128, colBase = blockIdx.x * 128;
    const int e0 = t * 8, e1 = (256 + t) * 8;
    const int r0 = e0 >> 5, c0 = e0 & 31;
    const int r1 = e1 >> 5, c1 = e1 & 31;

    f32x4 acc[4][4];
    f32x4 zf = {0.f, 0.f, 0.f, 0.f};
#pragma unroll
    for (int i = 0; i < 4; i++)
#pragma unroll
        for (int j = 0; j < 4; j++) acc[i][j] = zf;

    for (int k0 = 0; k0 < 1024; k0 += 32) {
        bf16x8 a0 = *(const bf16x8*)(A  + (size_t)(rowBase + r0) * 1024 + k0 + c0);
        bf16x8 a1 = *(const bf16x8*)(A  + (size_t)(rowBase + r1) * 1024 + k0 + c1);
        bf16x8 b0 = *(const bf16x8*)(Bt + (size_t)(colBase + r0) * 1024 + k0 + c0);
        bf16x8 b1 = *(const bf16x8*)(Bt + (size_t)(colBase + r1) * 1024 + k0 + c1);
        *(bf16x8*)(As + r0 * GS + c0) = a0;
        *(bf16x8*)(As + r1 * GS + c1) = a1;
        *(bf16x8*)(Bs + r0 * GS + c0) = b0;
        *(bf16x8*)(Bs + r1 * GS + c1) = b1;
        __syncthreads();
        bf16x8 afr[4], bfr[4];
#pragma unroll
        for (int mi = 0; mi < 4; mi++)
            afr[mi] = *(const bf16x8*)(As + (wr * 64 + mi * 16 + lane15) * GS + quad * 8);
#pragma unroll
        for (int ni = 0; ni < 4; ni++)
            bfr[ni] = *(const bf16x8*)(Bs + (wc * 64 + ni * 16 + lane15) * GS + quad * 8);
#pragma unroll
        for (int mi = 0; mi < 4; mi++)
#pragma unroll
            for (int ni = 0; ni < 4; ni++)
                acc[mi][ni] = __builtin_amdgcn_mfma_f32_16x16x32_bf16(afr[mi], bfr[ni], acc[mi][ni], 0, 0, 0);
        __syncthreads();
    }

#pragma unroll
    for (int ni = 0; ni < 4; ni++) {
        int col = colBase + wc * 64 + ni * 16 + lane15;
        float bias = bia[col];
#pragma unroll
        for (int mi = 0; mi < 4; mi++) {
#pragma unroll
            for (int r = 0; r < 4; r++) {
                int row = rowBase + wr * 64 + mi * 16 + quad * 4 + r;
                out[(size_t)row * 1024 + col] = acc[mi][ni][r] + bias;
            }
        }
    }
}

// ---------------------------------------------------------------------------
// Flash attention, fixed-max softmax (scores bounded; clamped at 80 in
// log2 domain), row-sums via ones-MFMA, double-buffered K/V staging.
// One block per (qtile64, bh); 4 waves x 16 q-rows.
// Q,K bf16 [B,H,L,DK]; V bf16 [B,H,DK,L]. attn out [B,L,H,DK].
// ---------------------------------------------------------------------------
#define FS 72   // flash LDS row stride (bf16 elems) for 64-wide tiles

__global__ __launch_bounds__(256, 2) void flash_kernel(
    const bf16_t* __restrict__ QKV, const int* __restrict__ mask,
    const int* __restrict__ flags, bf16_t* __restrict__ attnout)
{
    __shared__ bf16_t Ks[2][64 * FS];
    __shared__ bf16_t Vs[2][64 * FS];
    __shared__ bf16_t Ps[4 * 16 * FS];
    const int t = threadIdx.x, w = t >> 6, lane = t & 63;
    const int lane15 = lane & 15, quad = lane >> 4;
    const int qt = blockIdx.x, bh = blockIdx.y;
    const int b = bh >> 4, h = bh & 15;
    const bf16_t* Q  = QKV;
    const bf16_t* K  = QKV + 4194304;
    const bf16_t* Vt = QKV + 8388608;
    const int qrow0 = qt * 64 + w * 16;

    const bf16_t* qb = Q + ((size_t)bh * 2048 + qrow0 + lane15) * 64;
    bf16x8 aq0 = *(const bf16x8*)(qb + quad * 8);
    bf16x8 aq1 = *(const bf16x8*)(qb + 32 + quad * 8);
#pragma unroll
    for (int j = 0; j < 8; j++) {       // exact: *2^-3 (keeps bf16 mantissa)
        aq0[j] = (bf16_t)((float)aq0[j] * 0.125f);
        aq1[j] = (bf16_t)((float)aq1[j] * 0.125f);
    }

    f32x4 o[4];
    f32x4 zf = {0.f, 0.f, 0.f, 0.f};
#pragma unroll
    for (int df = 0; df < 4; df++) o[df] = zf;
    f32x4 lsum = zf;                    // row-sum accumulator (all cols equal)
    bf16_t* Pw = Ps + w * 16 * FS;
    bf16x8 ones;
#pragma unroll
    for (int j = 0; j < 8; j++) ones[j] = (bf16_t)1.0f;

    const int e0 = t * 8, e1 = (256 + t) * 8;
    const int kr0 = e0 >> 6, kc0 = e0 & 63, kr1 = e1 >> 6, kc1 = e1 & 63;
    const int* flagrow = flags + (b * 32 + qt) * 32;
    const bf16_t* Kb  = K  + (size_t)bh * 2048 * 64;
    const bf16_t* Vtb = Vt + (size_t)bh * 64 * 2048;

    // prologue: stage tile 0 into buffer 0
    {
        bf16x8 k0v = *(const bf16x8*)(Kb  + (size_t)kr0 * 64 + kc0);
        bf16x8 k1v = *(const bf16x8*)(Kb  + (size_t)kr1 * 64 + kc1);
        bf16x8 v0v = *(const bf16x8*)(Vtb + (size_t)kr0 * 2048 + kc0);
        bf16x8 v1v = *(const bf16x8*)(Vtb + (size_t)kr1 * 2048 + kc1);
        *(bf16x8*)(Ks[0] + kr0 * FS + kc0) = k0v;
        *(bf16x8*)(Ks[0] + kr1 * FS + kc1) = k1v;
        *(bf16x8*)(Vs[0] + kr0 * FS + kc0) = v0v;
        *(bf16x8*)(Vs[0] + kr1 * FS + kc1) = v1v;
    }
    __syncthreads();

    for (int kt = 0; kt < 32; kt++) {
        const int cur = kt & 1, nxt = cur ^ 1;
        bf16x8 k0v, k1v, v0v, v1v;
        if (kt + 1 < 32) {              // issue next-tile global loads early
            int kn = (kt + 1) * 64;
            k0v = *(const bf16x8*)(Kb  + (size_t)(kn + kr0) * 64 + kc0);
            k1v = *(const bf16x8*)(Kb  + (size_t)(kn + kr1) * 64 + kc1);
            v0v = *(const bf16x8*)(Vtb + (size_t)kr0 * 2048 + kn + kc0);
            v1v = *(const bf16x8*)(Vtb + (size_t)kr1 * 2048 + kn + kc1);
        }

        f32x4 sf[4];
#pragma unroll
        for (int nf = 0; nf < 4; nf++) {
            f32x4 a = zf;
            bf16x8 kb0 = *(const bf16x8*)(Ks[cur] + (nf * 16 + lane15) * FS + quad * 8);
            bf16x8 kb1 = *(const bf16x8*)(Ks[cur] + (nf * 16 + lane15) * FS + 32 + quad * 8);
            a = __builtin_amdgcn_mfma_f32_16x16x32_bf16(aq0, kb0, a, 0, 0, 0);
            a = __builtin_amdgcn_mfma_f32_16x16x32_bf16(aq1, kb1, a, 0, 0, 0);
            sf[nf] = a * 1.44269504f;   // -> log2 domain
        }
        if (kt + 1 < 32) {              // park next tile in the idle buffer
            *(bf16x8*)(Ks[nxt] + kr0 * FS + kc0) = k0v;
            *(bf16x8*)(Ks[nxt] + kr1 * FS + kc1) = k1v;
            *(bf16x8*)(Vs[nxt] + kr0 * FS + kc0) = v0v;
            *(bf16x8*)(Vs[nxt] + kr1 * FS + kc1) = v1v;
        }
        if (!flagrow[kt]) {             // slow path: per-element mask
#pragma unroll
            for (int nf = 0; nf < 4; nf++)
#pragma unroll
                for (int r = 0; r < 4; r++) {
                    int qrow = qrow0 + quad * 4 + r;
                    int kpos = kt * 64 + nf * 16 + lane15;
                    if (mask[((size_t)b * 2048 + qrow) * 2048 + kpos] == 0)
                        sf[nf][r] = -1e30f;
                }
        }
        // P = exp2(clamped scores); no running max (scores bounded)
#pragma unroll
        for (int nf = 0; nf < 4; nf++)
#pragma unroll
            for (int r = 0; r < 4; r++)
                Pw[(quad * 4 + r) * FS + nf * 16 + lane15] =
                    (bf16_t)exp2f(fminf(sf[nf][r], 80.f));

        bf16x8 pa0 = *(const bf16x8*)(Pw + lane15 * FS + quad * 8);
        bf16x8 pa1 = *(const bf16x8*)(Pw + lane15 * FS + 32 + quad * 8);
        lsum = __builtin_amdgcn_mfma_f32_16x16x32_bf16(pa0, ones, lsum, 0, 0, 0);
        lsum = __builtin_amdgcn_mfma_f32_16x16x32_bf16(pa1, ones, lsum, 0, 0, 0);
#pragma unroll
        for (int df = 0; df < 4; df++) {
            bf16x8 vb0 = *(const bf16x8*)(Vs[cur] + (df * 16 + lane15) * FS + quad * 8);
            bf16x8 vb1 = *(const bf16x8*)(Vs[cur] + (df * 16 + lane15) * FS + 32 + quad * 8);
            o[df] = __builtin_amdgcn_mfma_f32_16x16x32_bf16(pa0, vb0, o[df], 0, 0, 0);
            o[df] = __builtin_amdgcn_mfma_f32_16x16x32_bf16(pa1, vb1, o[df], 0, 0, 0);
        }
        __syncthreads();                // next buffer fully written; cur free
    }
    // attn out: [B,L,H,DK]
#pragma unroll
    for (int r = 0; r < 4; r++) {
        float inv = 1.0f / lsum[r];
        size_t row = (size_t)b * 2048 + qrow0 + quad * 4 + r;
#pragma unroll
        for (int df = 0; df < 4; df++)
            attnout[(row * 16 + h) * 64 + df * 16 + lane15] = (bf16_t)(o[df][r] * inv);
    }
}

// ---------------------------------------------------------------------------
// Inter-head attention: one wave per position (b,l). attn is [B,L,H,DK].
// ---------------------------------------------------------------------------
__global__ __launch_bounds__(256, 2) void interhead_kernel(
    const bf16_t* __restrict__ attn,
    const bf16_t* __restrict__ whqT, const float* __restrict__ bhq,
    const bf16_t* __restrict__ whkT, const float* __restrict__ bhk,
    const bf16_t* __restrict__ whvT, const float* __restrict__ bhv,
    bf16_t* __restrict__ concat)
{
    __shared__ bf16_t lds[4 * 4608];
    const int t = threadIdx.x, w = t >> 6, lane = t & 63;
    const int lane15 = lane & 15, quad = lane >> 4;
    bf16_t* Qh  = lds + w * 4608;   // [16][64]
    bf16_t* Kh  = Qh + 1024;        // [16][64]
    bf16_t* VhT = Kh + 1024;        // [64][32] (k-padded)
    bf16_t* P16 = VhT + 2048;       // [16][32] (k-padded)
    const int p = blockIdx.x * 4 + w;

    bf16x8 z8 = {(bf16_t)0.f, (bf16_t)0.f, (bf16_t)0.f, (bf16_t)0.f,
                 (bf16_t)0.f, (bf16_t)0.f, (bf16_t)0.f, (bf16_t)0.f};
    ((bf16x8*)P16)[lane] = z8;
#pragma unroll
    for (int i = 0; i < 4; i++) ((bf16x8*)VhT)[i * 64 + lane] = z8;

    const bf16_t* hb = attn + ((size_t)p * 16 + lane15) * 64;
    bf16x8 ha0 = *(const bf16x8*)(hb + quad * 8);
    bf16x8 ha1 = *(const bf16x8*)(hb + 32 + quad * 8);

    const bf16_t* Wt[3] = {whqT, whkT, whvT};
    const float*  Bb[3] = {bhq, bhk, bhv};
    f32x4 zf = {0.f, 0.f, 0.f, 0.f};
#pragma unroll
    for (int m3 = 0; m3 < 3; m3++) {
#pragma unroll
        for (int nf = 0; nf < 4; nf++) {
            f32x4 acc = zf;
            bf16x8 wb0 = *(const bf16x8*)(Wt[m3] + (nf * 16 + lane15) * 64 + quad * 8);
            bf16x8 wb1 = *(const bf16x8*)(Wt[m3] + (nf * 16 + lane15) * 64 + 32 + quad * 8);
            acc = __builtin_amdgcn_mfma_f32_16x16x32_bf16(ha0, wb0, acc, 0, 0, 0);
            acc = __builtin_amdgcn_mfma_f32_16x16x32_bf16(ha1, wb1, acc, 0, 0, 0);
            float bias = Bb[m3][nf * 16 + lane15];
#pragma unroll
            for (int r = 0; r < 4; r++) {
                float v = acc[r] + bias;
                if (m3 == 0) v *= 0.125f;   // fold inter scale into Qh (exact)
                if (m3 == 2) VhT[(nf * 16 + lane15) * 32 + quad * 4 + r] = (bf16_t)v;
                else if (m3 == 0) Qh[(quad * 4 + r) * 64 + nf * 16 + lane15] = (bf16_t)v;
                else Kh[(quad * 4 + r) * 64 + nf * 16 + lane15] = (bf16_t)v;
            }
        }
    }
    __syncthreads();

    bf16x8 qa0 = *(const bf16x8*)(Qh + lane15 * 64 + quad * 8);
    bf16x8 qa1 = *(const bf16x8*)(Qh + lane15 * 64 + 32 + quad * 8);
    bf16x8 kb0 = *(const bf16x8*)(Kh + lane15 * 64 + quad * 8);
    bf16x8 kb1 = *(const bf16x8*)(Kh + lane15 * 64 + 32 + quad * 8);
    f32x4 s = zf;
    s = __builtin_amdgcn_mfma_f32_16x16x32_bf16(qa0, kb0, s, 0, 0, 0);
    s = __builtin_amdgcn_mfma_f32_16x16x32_bf16(qa1, kb1, s, 0, 0, 0);
#pragma unroll
    for (int r = 0; r < 4; r++) {
        float v = s[r];
        float mx = v;
        mx = fmaxf(mx, __shfl_xor(mx, 1));
        mx = fmaxf(mx, __shfl_xor(mx, 2));
        mx = fmaxf(mx, __shfl_xor(mx, 4));
        mx = fmaxf(mx, __shfl_xor(mx, 8));
        float pv = __expf(v - mx);
        float sm = pv;
        sm += __shfl_xor(sm, 1);
        sm += __shfl_xor(sm, 2);
        sm += __shfl_xor(sm, 4);
        sm += __shfl_xor(sm, 8);
        P16[(quad * 4 + r) * 32 + lane15] = (bf16_t)(pv / sm);
    }
    __syncthreads();

    bf16x8 pa = *(const bf16x8*)(P16 + lane15 * 32 + quad * 8);
    bf16_t* outp = concat + (size_t)p * 1024;
#pragma unroll
    for (int df = 0; df < 4; df++) {
        bf16x8 vb = *(const bf16x8*)(VhT + (df * 16 + lane15) * 32 + quad * 8);
        f32x4 mix = zf;
        mix = __builtin_amdgcn_mfma_f32_16x16x32_bf16(pa, vb, mix, 0, 0, 0);
#pragma unroll
        for (int r = 0; r < 4; r++)
            outp[(quad * 4 + r) * 64 + df * 16 + lane15] = (bf16_t)mix[r];
    }
}

// ---------------------------------------------------------------------------
extern "C" void kernel_launch(void* const* d_in, const int* in_sizes, int n_in,
                              void* d_out, int out_size, void* d_ws, size_t ws_size,
                              hipStream_t stream)
{
    const float* q_in = (const float*)d_in[0];
    const float* k_in = (const float*)d_in[1];
    const float* v_in = (const float*)d_in[2];
    const int*   mask = (const int*)d_in[3];
    const float* wq = (const float*)d_in[4];
    const float* bq = (const float*)d_in[5];
    const float* wk = (const float*)d_in[6];
    const float* bk = (const float*)d_in[7];
    const float* wv = (const float*)d_in[8];
    const float* bv = (const float*)d_in[9];
    const float* wo = (const float*)d_in[10];
    const float* bo = (const float*)d_in[11];
    const float* whq = (const float*)d_in[12];
    const float* bhq = (const float*)d_in[13];
    const float* whk = (const float*)d_in[14];
    const float* bhk = (const float*)d_in[15];
    const float* whv = (const float*)d_in[16];
    const float* bhv = (const float*)d_in[17];
    float* out = (float*)d_out;         // [4096][1024] f32 = 16 MB

    char* ws = (char*)d_ws;
    bf16_t* qkvb  = (bf16_t*)ws;                       // 24 MB: Q|K|Vt
    bf16_t* concat = qkvb;                             // Q region, post-flash
    bf16_t* woT   = (bf16_t*)(ws + 8u * 1024 * 1024);  // K region, post-flash
    bf16_t* whqT  = (bf16_t*)(ws + 10u * 1024 * 1024);
    bf16_t* whkT  = whqT + 4096;
    bf16_t* whvT  = whqT + 8192;
    bf16_t* attnb = (bf16_t*)d_out;                    // 8 MB bf16 in d_out
    bf16_t* wqkvT = (bf16_t*)((char*)d_out + 8u * 1024 * 1024);
    int*    flags = (int*)((char*)d_out + 14u * 1024 * 1024);

    maskflags_kernel<<<2048, 256, 0, stream>>>(mask, flags);
    transpose_qkvw_kernel<<<dim3(16, 16, 3), 256, 0, stream>>>(wq, wk, wv, wqkvT);
    gemm_qkv_kernel<<<dim3(8, 32, 3), 256, 0, stream>>>(q_in, k_in, v_in, wqkvT, bq, bk, bv, qkvb);
    flash_kernel<<<dim3(32, 32), 256, 0, stream>>>(qkvb, mask, flags, attnb);
    transpose_one_kernel<<<dim3(16, 16), 256, 0, stream>>>(wo, woT);
    transpose_small_kernel<<<3, 256, 0, stream>>>(whq, whk, whv, whqT, whkT, whvT);
    interhead_kernel<<<1024, 256, 0, stream>>>(attnb, whqT, bhq, whkT, bhk, whvT, bhv, concat);
    gemm_out_kernel<<<dim3(8, 32), 256, 0, stream>>>(concat, woT, bo, out);
    (void)in_sizes; (void)n_in; (void)out_size; (void)ws_size;
}